// Round 1
// baseline (788.620 us; speedup 1.0000x reference)
//
#include <hip/hip_runtime.h>
#include <math.h>

#define D      64     // feature dim (16 float4 chunks)
#define KC     10     // clusters
#define BLOCK  256
#define WPB    4      // waves per block
#define NQ     (3*KC) // 30 partial quantities: pos[10], neg[10], cnt[10]

// ---------------------------------------------------------------------------
// Main kernel: wave-synchronous 64-row tiles.
//   - Each wave stages a 64x64-float tile: coalesced global float4 loads
//     (lane l loads chunk g = i*64+l -> 1024B contiguous per instruction),
//     stored to LDS with XOR swizzle slot = r*16 + (c ^ (r&15)) so the
//     row-per-lane ds_read_b128 is bank-conflict-free per 8-lane phase.
//   - Compute: lane owns row r=lane; 10 dot products vs centers (uniform
//     LDS reads -> broadcast), clip, exp, accumulate pos/neg/count.
//   - No block barriers in the loop; per-wave s_waitcnt lgkmcnt(0) orders
//     LDS write->read (same wave, in-order DS pipe + asm memory clobber).
//   - Deterministic: butterfly shuffle reduce, per-wave partials to ws.
// ---------------------------------------------------------------------------
__global__ __launch_bounds__(BLOCK, 2) void cl_main(
    const float* __restrict__ feat, const int* __restrict__ pred,
    const float* __restrict__ centers, float* __restrict__ ws,
    int N, int nPart)
{
    __shared__ float c_lds[KC * D];
    __shared__ float tile[WPB][64 * D];   // per-wave 16 KB region

    const int tid = threadIdx.x;
    // stage centers (2.5 KB) once; the only block barrier, before divergence
    if (tid < KC * D / 4)
        ((float4*)c_lds)[tid] = ((const float4*)centers)[tid];
    __syncthreads();

    const int wave = tid >> 6;
    const int lane = tid & 63;
    const int wgid = blockIdx.x * WPB + wave;    // 0..nPart-1
    float* tw = tile[wave];

    float posA[KC], negA[KC], cntA[KC];
#pragma unroll
    for (int k = 0; k < KC; ++k) { posA[k] = 0.f; negA[k] = 0.f; cntA[k] = 0.f; }

    const int nTiles = (N + 63) >> 6;
    for (int t = wgid; t < nTiles; t += nPart) {
        const int base = t << 6;

        // WAR fence: previous iteration's tile reads must complete before overwrite
        asm volatile("s_waitcnt lgkmcnt(0)" ::: "memory");

        // ---- stage 64 rows (1024 chunks of 16B), coalesced ----
#pragma unroll
        for (int i = 0; i < 16; ++i) {
            const int g = (i << 6) + lane;      // tile chunk id
            const int r = g >> 4;               // tile row 0..63
            const int c = g & 15;               // chunk within row
            const int grow = base + r;
            float4 v = make_float4(0.f, 0.f, 0.f, 0.f);
            if (grow < N) v = ((const float4*)feat)[(size_t)grow * 16 + c];
            ((float4*)tw)[(r << 4) + (c ^ (r & 15))] = v;   // XOR-swizzled
        }
        // RAW fence: stage writes visible to this wave's reads
        asm volatile("s_waitcnt lgkmcnt(0)" ::: "memory");

        // ---- compute: lane owns row base+lane ----
        const int grow = base + lane;
        const bool act = grow < N;
        float s[KC];
#pragma unroll
        for (int k = 0; k < KC; ++k) s[k] = 0.f;

        const float4* trow = ((const float4*)tw) + (lane << 4);
#pragma unroll
        for (int c = 0; c < 16; ++c) {
            const float4 f = trow[c ^ (lane & 15)];
#pragma unroll
            for (int k = 0; k < KC; ++k) {
                const float4 cv = ((const float4*)c_lds)[(k << 4) + c]; // uniform -> broadcast
                s[k] += f.x * cv.x + f.y * cv.y + f.z * cv.z + f.w * cv.w;
            }
        }

        const int p = act ? pred[grow] : -1;
#pragma unroll
        for (int k = 0; k < KC; ++k) {
            float sc = s[k] * 0.5f;                       // / tau (=2)
            sc = fminf(fmaxf(sc, -10.f), 10.f);           // clip
            const float e = __expf(sc);
            if (act) {
                negA[k] += e;
                if (p == k) { posA[k] += e; cntA[k] += 1.f; }
            }
        }
    }

    // ---- deterministic wave butterfly reduce; partials laid out [q][nPart] ----
#pragma unroll
    for (int k = 0; k < KC; ++k) {
        float v0 = posA[k], v1 = negA[k], v2 = cntA[k];
#pragma unroll
        for (int off = 32; off; off >>= 1) {
            v0 += __shfl_xor(v0, off, 64);
            v1 += __shfl_xor(v1, off, 64);
            v2 += __shfl_xor(v2, off, 64);
        }
        if (lane == 0) {
            ws[(k)          * nPart + wgid] = v0;
            ws[(KC + k)     * nPart + wgid] = v1;
            ws[(2 * KC + k) * nPart + wgid] = v2;
        }
    }
}

// ---------------------------------------------------------------------------
// Finalize: one block; deterministic tree-sum of nPart partials per quantity,
// then thread 0 computes the scalar loss exactly per the reference semantics.
// ---------------------------------------------------------------------------
__global__ __launch_bounds__(BLOCK) void cl_final(
    const float* __restrict__ ws, float* __restrict__ out, int N, int nPart)
{
    const int tid = threadIdx.x;
    float acc[NQ];
#pragma unroll
    for (int q = 0; q < NQ; ++q) acc[q] = 0.f;

    for (int i = tid; i < nPart; i += BLOCK) {
#pragma unroll
        for (int q = 0; q < NQ; ++q) acc[q] += ws[q * nPart + i];   // coalesced
    }

    const int wave = tid >> 6;
    const int lane = tid & 63;
    __shared__ float sred[WPB][NQ];
#pragma unroll
    for (int q = 0; q < NQ; ++q) {
        float v = acc[q];
#pragma unroll
        for (int off = 32; off; off >>= 1) v += __shfl_xor(v, off, 64);
        if (lane == 0) sred[wave][q] = v;
    }
    __syncthreads();

    if (tid == 0) {
        float tot = 0.f;
        int nv = 0;
#pragma unroll
        for (int k = 0; k < KC; ++k) {
            const float pos_s = sred[0][k] + sred[1][k] + sred[2][k] + sred[3][k];
            const float neg_s = sred[0][KC+k] + sred[1][KC+k] + sred[2][KC+k] + sred[3][KC+k];
            const float cnt   = sred[0][2*KC+k] + sred[1][2*KC+k] + sred[2][2*KC+k] + sred[3][2*KC+k];
            const float neg = neg_s / (float)N;                 // e.mean(axis=0)
            const float pos = pos_s / fmaxf(cnt, 1.f);          // sum / max(count,1)
            const float lt  = -logf(pos / (neg + 1e-8f));
            const bool valid = (cnt > 0.f) && (cnt < (float)N) &&
                               (pos > 1e-8f) && (neg > 1e-8f) && isfinite(lt);
            if (valid) { tot += lt; ++nv; }
        }
        out[0] = (nv > 0 ? tot / (float)nv : 0.f) * 5.0f;   // * weight
    }
}

extern "C" void kernel_launch(void* const* d_in, const int* in_sizes, int n_in,
                              void* d_out, int out_size, void* d_ws, size_t ws_size,
                              hipStream_t stream) {
    const float* feat    = (const float*)d_in[0];
    const int*   pred    = (const int*)d_in[1];
    const float* centers = (const float*)d_in[2];
    float*       out     = (float*)d_out;
    const int N = in_sizes[1];          // 500000

    // nPart waves of partials; cap by workspace (NQ floats per wave partial)
    int nPart = 2048;                               // 512 blocks * 4 waves
    const int maxPart = (int)(ws_size / (NQ * sizeof(float)));
    if (nPart > maxPart) nPart = maxPart & ~(WPB - 1);
    if (nPart < WPB) nPart = WPB;
    const int nBlocks = nPart / WPB;

    hipLaunchKernelGGL(cl_main, dim3(nBlocks), dim3(BLOCK), 0, stream,
                       feat, pred, centers, (float*)d_ws, N, nPart);
    hipLaunchKernelGGL(cl_final, dim3(1), dim3(BLOCK), 0, stream,
                       (const float*)d_ws, out, N, nPart);
}

// Round 2
// 270.190 us; speedup vs baseline: 2.9188x; 2.9188x over previous
//
#include <hip/hip_runtime.h>
#include <math.h>

#define D4     16     // float4 chunks per 64-float row
#define KC     10     // clusters
#define BLOCK  256
#define WPB    4      // waves per block
#define NQ     (3*KC) // pos[10], neg[10], cnt[10]
#define RPW    16     // rows per wave per iteration

// ---------------------------------------------------------------------------
// Register-only streaming kernel. No LDS tile, no asm fences.
// Lane role: g = lane>>2 (row within 16-row tile), s = lane&3 (chunk slot).
// Lane loads chunks {s, s+4, s+8, s+12} of its row (4x float4 = 64B).
// Per-instruction wave footprint: 16 x 64B contiguous segments; ci and ci+1
// cover each 128B line consecutively -> 1.0x HBM fetch.
// Dot partials reduced across the 4-lane group (shfl_xor 1,2); all 4 lanes
// accumulate the same row -> partial sums are exactly 4x; finalize corrects.
// Register double-buffer: prefetch tile t+nPart while computing tile t.
// ---------------------------------------------------------------------------
__global__ __launch_bounds__(BLOCK, 4) void cl_main(
    const float* __restrict__ feat, const int* __restrict__ pred,
    const float* __restrict__ centers, float* __restrict__ ws,
    int N, int nPart)
{
    __shared__ float4 c_lds[KC * D4];   // 2.5 KB
    const int tid = threadIdx.x;
    if (tid < KC * D4)
        c_lds[tid] = ((const float4*)centers)[tid];
    __syncthreads();

    const int lane = tid & 63;
    const int wave = tid >> 6;
    const int wgid = blockIdx.x * WPB + wave;   // 0..nPart-1
    const int s4   = lane & 3;
    const int g    = lane >> 2;

    float posA[KC], negA[KC], cntA[KC];
#pragma unroll
    for (int k = 0; k < KC; ++k) { posA[k] = 0.f; negA[k] = 0.f; cntA[k] = 0.f; }

    const int nTiles = (N + RPW - 1) / RPW;

    // ---- prefetch tile t0 ----
    int t = wgid;
    bool have = (t < nTiles);
    float4 fa0, fa1, fa2, fa3;
    int pcur = 0;
    if (have) {
        const int row = t * RPW + g;
        const int rc  = row < N ? row : N - 1;
        const float4* rp = (const float4*)feat + (size_t)rc * D4 + s4;
        fa0 = rp[0]; fa1 = rp[4]; fa2 = rp[8]; fa3 = rp[12];
        pcur = pred[rc];
    }

    while (have) {
        // ---- prefetch next tile into fb while computing current ----
        const int tn = t + nPart;
        const bool haveN = (tn < nTiles);
        float4 fb0, fb1, fb2, fb3;
        int pnext = 0;
        if (haveN) {
            const int row = tn * RPW + g;
            const int rc  = row < N ? row : N - 1;
            const float4* rp = (const float4*)feat + (size_t)rc * D4 + s4;
            fb0 = rp[0]; fb1 = rp[4]; fb2 = rp[8]; fb3 = rp[12];
            pnext = pred[rc];
        }

        // ---- compute current tile ----
        float sd[KC];
#pragma unroll
        for (int k = 0; k < KC; ++k) sd[k] = 0.f;

#pragma unroll
        for (int k = 0; k < KC; ++k) {
            const float4 c0 = c_lds[k * D4 + 0 * 4 + s4];
            const float4 c1 = c_lds[k * D4 + 1 * 4 + s4];
            const float4 c2 = c_lds[k * D4 + 2 * 4 + s4];
            const float4 c3 = c_lds[k * D4 + 3 * 4 + s4];
            sd[k] = fa0.x*c0.x + fa0.y*c0.y + fa0.z*c0.z + fa0.w*c0.w
                  + fa1.x*c1.x + fa1.y*c1.y + fa1.z*c1.z + fa1.w*c1.w
                  + fa2.x*c2.x + fa2.y*c2.y + fa2.z*c2.z + fa2.w*c2.w
                  + fa3.x*c3.x + fa3.y*c3.y + fa3.z*c3.z + fa3.w*c3.w;
        }
        // reduce across the 4-lane group (lanes differing in bits 0,1)
#pragma unroll
        for (int k = 0; k < KC; ++k) {
            sd[k] += __shfl_xor(sd[k], 1, 64);
            sd[k] += __shfl_xor(sd[k], 2, 64);
        }

        const int row = t * RPW + g;
        const float actf = (row < N) ? 1.f : 0.f;
#pragma unroll
        for (int k = 0; k < KC; ++k) {
            float sc = sd[k] * 0.5f;                    // / tau (=2)
            sc = fminf(fmaxf(sc, -10.f), 10.f);         // clip
            const float e = __expf(sc) * actf;          // zero if inactive row
            negA[k] += e;
            if (pcur == k) { posA[k] += e; cntA[k] += actf; }
        }

        // ---- rotate buffers ----
        t = tn; have = haveN;
        fa0 = fb0; fa1 = fb1; fa2 = fb2; fa3 = fb3;
        pcur = pnext;
    }

    // ---- deterministic 64-lane butterfly; partials laid out [q][nPart] ----
#pragma unroll
    for (int k = 0; k < KC; ++k) {
        float v0 = posA[k], v1 = negA[k], v2 = cntA[k];
#pragma unroll
        for (int off = 32; off; off >>= 1) {
            v0 += __shfl_xor(v0, off, 64);
            v1 += __shfl_xor(v1, off, 64);
            v2 += __shfl_xor(v2, off, 64);
        }
        if (lane == 0) {
            ws[(k)          * nPart + wgid] = v0;   // 4x pos sum
            ws[(KC + k)     * nPart + wgid] = v1;   // 4x neg sum
            ws[(2 * KC + k) * nPart + wgid] = v2;   // 4x count
        }
    }
}

// ---------------------------------------------------------------------------
// Finalize: one block; deterministic tree-sum of nPart partials per quantity.
// All sums are 4x the true values (4 lanes accumulated each row).
// ---------------------------------------------------------------------------
__global__ __launch_bounds__(BLOCK) void cl_final(
    const float* __restrict__ ws, float* __restrict__ out, int N, int nPart)
{
    const int tid = threadIdx.x;
    float acc[NQ];
#pragma unroll
    for (int q = 0; q < NQ; ++q) acc[q] = 0.f;

    for (int i = tid; i < nPart; i += BLOCK) {
#pragma unroll
        for (int q = 0; q < NQ; ++q) acc[q] += ws[q * nPart + i];   // coalesced
    }

    const int wave = tid >> 6;
    const int lane = tid & 63;
    __shared__ float sred[WPB][NQ];
#pragma unroll
    for (int q = 0; q < NQ; ++q) {
        float v = acc[q];
#pragma unroll
        for (int off = 32; off; off >>= 1) v += __shfl_xor(v, off, 64);
        if (lane == 0) sred[wave][q] = v;
    }
    __syncthreads();

    if (tid == 0) {
        float tot = 0.f;
        int nv = 0;
#pragma unroll
        for (int k = 0; k < KC; ++k) {
            const float pos4 = sred[0][k]       + sred[1][k]       + sred[2][k]       + sred[3][k];
            const float neg4 = sred[0][KC+k]    + sred[1][KC+k]    + sred[2][KC+k]    + sred[3][KC+k];
            const float cnt4 = sred[0][2*KC+k]  + sred[1][2*KC+k]  + sred[2][2*KC+k]  + sred[3][2*KC+k];
            const float neg = neg4 / (4.0f * (float)N);        // e.mean(axis=0)
            const float pos = pos4 / fmaxf(cnt4, 4.0f);        // sum / max(count,1), 4x/4x
            const float lt  = -logf(pos / (neg + 1e-8f));
            const bool valid = (cnt4 > 0.f) && (cnt4 < 4.0f * (float)N) &&
                               (pos > 1e-8f) && (neg > 1e-8f) && isfinite(lt);
            if (valid) { tot += lt; ++nv; }
        }
        out[0] = (nv > 0 ? tot / (float)nv : 0.f) * 5.0f;   // * weight
    }
}

extern "C" void kernel_launch(void* const* d_in, const int* in_sizes, int n_in,
                              void* d_out, int out_size, void* d_ws, size_t ws_size,
                              hipStream_t stream) {
    const float* feat    = (const float*)d_in[0];
    const int*   pred    = (const int*)d_in[1];
    const float* centers = (const float*)d_in[2];
    float*       out     = (float*)d_out;
    const int N = in_sizes[1];          // 500000

    int nPart = 4096;                               // 1024 blocks * 4 waves
    const int maxPart = (int)(ws_size / (NQ * sizeof(float)));
    if (nPart > maxPart) nPart = maxPart & ~(WPB - 1);
    if (nPart < WPB) nPart = WPB;
    const int nBlocks = nPart / WPB;

    hipLaunchKernelGGL(cl_main, dim3(nBlocks), dim3(BLOCK), 0, stream,
                       feat, pred, centers, (float*)d_ws, N, nPart);
    hipLaunchKernelGGL(cl_final, dim3(1), dim3(BLOCK), 0, stream,
                       (const float*)d_ws, out, N, nPart);
}

// Round 4
// 237.972 us; speedup vs baseline: 3.3139x; 1.1354x over previous
//
#include <hip/hip_runtime.h>
#include <math.h>

#define D4     16     // float4 chunks per 64-float row
#define KC     10     // clusters
#define BLOCK  256
#define WPB    4      // waves per block
#define NQ     (3*KC) // pos[10], neg[10], cnt[10]
#define RPW    16     // rows per wave per iteration

// ---------------------------------------------------------------------------
// Register-lean streaming kernel (no double-buffer, no runtime-indexed arrays).
// Lane role: g = lane>>2 (row in 16-row tile), s4 = lane&3 (chunk slot).
// Lane loads chunks {s4, s4+4, s4+8, s4+12} of its row (4x float4 = 64B);
// the 4 load instructions together cover each 4KB tile exactly once (64B
// sectors touched once) -> 1.0x HBM fetch.
// Cluster ownership: lane s4 owns k in {s4, s4+4, s4+8} -> 9 accumulators
// per lane (not 30), <=3 exp per lane per row. Dot sums all-reduced over the
// 4-lane group (xor 1,2); owned sums picked via static cndmask chain.
// Deterministic: fixed butterfly orders, per-wave partials, tree finalize.
// ---------------------------------------------------------------------------
__global__ __launch_bounds__(BLOCK, 8) void cl_main(
    const float* __restrict__ feat, const int* __restrict__ pred,
    const float* __restrict__ centers, float* __restrict__ ws,
    int N, int nPart)
{
    __shared__ float4 c_lds[KC * D4];   // 2.5 KB
    const int tid = threadIdx.x;
    if (tid < KC * D4)
        c_lds[tid] = ((const float4*)centers)[tid];
    __syncthreads();

    const int lane = tid & 63;
    const int wave = tid >> 6;
    const int wgid = blockIdx.x * WPB + wave;   // 0..nPart-1
    const int s4   = lane & 3;
    const int g    = lane >> 2;

    // lane's clusters: k = s4, s4+4, s4+8 (last valid only for s4<2)
    float pos0=0.f,pos1=0.f,pos2=0.f, neg0=0.f,neg1=0.f,neg2=0.f,
          cnt0=0.f,cnt1=0.f,cnt2=0.f;

    const int nTiles = (N + RPW - 1) / RPW;
    for (int t = wgid; t < nTiles; t += nPart) {
        const int row  = t * RPW + g;
        const int rc   = row < N ? row : N - 1;
        const float4* rp = (const float4*)feat + (size_t)rc * D4 + s4;
        const float4 f0 = rp[0], f1 = rp[4], f2 = rp[8], f3 = rp[12];
        const int   pcur = pred[rc];
        const float actf = (row < N) ? 1.f : 0.f;

        float sd[KC];
#pragma unroll
        for (int k = 0; k < KC; ++k) {
            const float4 c0 = c_lds[k * D4 + 0 + s4];
            const float4 c1 = c_lds[k * D4 + 4 + s4];
            const float4 c2 = c_lds[k * D4 + 8 + s4];
            const float4 c3 = c_lds[k * D4 + 12 + s4];
            sd[k] = f0.x*c0.x + f0.y*c0.y + f0.z*c0.z + f0.w*c0.w
                  + f1.x*c1.x + f1.y*c1.y + f1.z*c1.z + f1.w*c1.w
                  + f2.x*c2.x + f2.y*c2.y + f2.z*c2.z + f2.w*c2.w
                  + f3.x*c3.x + f3.y*c3.y + f3.z*c3.z + f3.w*c3.w;
        }
#pragma unroll
        for (int k = 0; k < KC; ++k) {
            sd[k] += __shfl_xor(sd[k], 1, 64);
            sd[k] += __shfl_xor(sd[k], 2, 64);
        }

        // static-index selection of the owned dot sums (no runtime indexing)
        const float sel0 = (s4 == 0) ? sd[0] : (s4 == 1) ? sd[1] : (s4 == 2) ? sd[2] : sd[3];
        const float sel1 = (s4 == 0) ? sd[4] : (s4 == 1) ? sd[5] : (s4 == 2) ? sd[6] : sd[7];
        const float sel2 = (s4 == 0) ? sd[8] : sd[9];       // garbage for s4>=2, masked below
        const float m2   = (s4 < 2) ? actf : 0.f;

        {   // k = s4
            float sc = fminf(fmaxf(sel0 * 0.5f, -10.f), 10.f);
            const float e = __expf(sc) * actf;
            neg0 += e;
            if (pcur == s4) { pos0 += e; cnt0 += actf; }
        }
        {   // k = s4 + 4
            float sc = fminf(fmaxf(sel1 * 0.5f, -10.f), 10.f);
            const float e = __expf(sc) * actf;
            neg1 += e;
            if (pcur == s4 + 4) { pos1 += e; cnt1 += actf; }
        }
        {   // k = s4 + 8 (only s4<2 real)
            float sc = fminf(fmaxf(sel2 * 0.5f, -10.f), 10.f);
            const float e = __expf(sc) * m2;
            neg2 += e;
            if (pcur == s4 + 8) { pos2 += e; cnt2 += m2; }  // pcur<10 => false for s4>=2
        }
    }

    // ---- reduce across the 16 lanes sharing this s4 (offsets 4..32) ----
#pragma unroll
    for (int off = 4; off <= 32; off <<= 1) {
        pos0 += __shfl_xor(pos0, off, 64); neg0 += __shfl_xor(neg0, off, 64); cnt0 += __shfl_xor(cnt0, off, 64);
        pos1 += __shfl_xor(pos1, off, 64); neg1 += __shfl_xor(neg1, off, 64); cnt1 += __shfl_xor(cnt1, off, 64);
        pos2 += __shfl_xor(pos2, off, 64); neg2 += __shfl_xor(neg2, off, 64); cnt2 += __shfl_xor(cnt2, off, 64);
    }

    if (lane < 4) {           // lane == s4; write partials [q][nPart]
        const int k0 = lane, k1 = lane + 4, k2 = lane + 8;
        ws[(k0)          * nPart + wgid] = pos0;
        ws[(KC + k0)     * nPart + wgid] = neg0;
        ws[(2 * KC + k0) * nPart + wgid] = cnt0;
        ws[(k1)          * nPart + wgid] = pos1;
        ws[(KC + k1)     * nPart + wgid] = neg1;
        ws[(2 * KC + k1) * nPart + wgid] = cnt1;
        if (k2 < KC) {
            ws[(k2)          * nPart + wgid] = pos2;
            ws[(KC + k2)     * nPart + wgid] = neg2;
            ws[(2 * KC + k2) * nPart + wgid] = cnt2;
        }
    }
}

// ---------------------------------------------------------------------------
// Finalize: one block; float4 coalesced reads, static accumulator indexing,
// deterministic tree combine, thread 0 computes the scalar loss.
// ---------------------------------------------------------------------------
__global__ __launch_bounds__(BLOCK) void cl_final(
    const float* __restrict__ ws, float* __restrict__ out, int N, int nPart)
{
    const int tid = threadIdx.x;
    const int np4 = nPart >> 2;                 // nPart multiple of 4 (WPB)
    const float4* w4 = (const float4*)ws;

    float acc[NQ];
#pragma unroll
    for (int q = 0; q < NQ; ++q) acc[q] = 0.f;

    for (int i = tid; i < np4; i += BLOCK) {
#pragma unroll
        for (int q = 0; q < NQ; ++q) {          // q static -> registers
            const float4 v = w4[q * np4 + i];   // coalesced
            acc[q] += (v.x + v.y) + (v.z + v.w);
        }
    }

    const int wave = tid >> 6;
    const int lane = tid & 63;
    __shared__ float sred[WPB][NQ];
#pragma unroll
    for (int q = 0; q < NQ; ++q) {
        float v = acc[q];
#pragma unroll
        for (int off = 32; off; off >>= 1) v += __shfl_xor(v, off, 64);
        if (lane == 0) sred[wave][q] = v;
    }
    __syncthreads();

    if (tid == 0) {
        float tot = 0.f;
        int nv = 0;
#pragma unroll
        for (int k = 0; k < KC; ++k) {
            const float pos_s = sred[0][k]      + sred[1][k]      + sred[2][k]      + sred[3][k];
            const float neg_s = sred[0][KC+k]   + sred[1][KC+k]   + sred[2][KC+k]   + sred[3][KC+k];
            const float cnt   = sred[0][2*KC+k] + sred[1][2*KC+k] + sred[2][2*KC+k] + sred[3][2*KC+k];
            const float neg = neg_s / (float)N;                 // e.mean(axis=0)
            const float pos = pos_s / fmaxf(cnt, 1.f);          // sum / max(count,1)
            const float lt  = -logf(pos / (neg + 1e-8f));
            const bool valid = (cnt > 0.f) && (cnt < (float)N) &&
                               (pos > 1e-8f) && (neg > 1e-8f) && isfinite(lt);
            if (valid) { tot += lt; ++nv; }
        }
        out[0] = (nv > 0 ? tot / (float)nv : 0.f) * 5.0f;   // * weight
    }
}

extern "C" void kernel_launch(void* const* d_in, const int* in_sizes, int n_in,
                              void* d_out, int out_size, void* d_ws, size_t ws_size,
                              hipStream_t stream) {
    const float* feat    = (const float*)d_in[0];
    const int*   pred    = (const int*)d_in[1];
    const float* centers = (const float*)d_in[2];
    float*       out     = (float*)d_out;
    const int N = in_sizes[1];          // 500000

    int nPart = 4096;                               // 1024 blocks * 4 waves
    const int maxPart = (int)(ws_size / (NQ * sizeof(float)));
    if (nPart > maxPart) nPart = maxPart & ~(WPB - 1);
    if (nPart < WPB) nPart = WPB;
    const int nBlocks = nPart / WPB;

    hipLaunchKernelGGL(cl_main, dim3(nBlocks), dim3(BLOCK), 0, stream,
                       feat, pred, centers, (float*)d_ws, N, nPart);
    hipLaunchKernelGGL(cl_final, dim3(1), dim3(BLOCK), 0, stream,
                       (const float*)d_ws, out, N, nPart);
}

// Round 5
// 57.044 us; speedup vs baseline: 13.8249x; 4.1718x over previous
//
#include <hip/hip_runtime.h>
#include <math.h>

#define D4     16     // float4 chunks per 64-float row
#define KC     10     // clusters
#define BLOCK  256
#define WPB    4      // waves per block
#define NQ     (3*KC) // pos[10], neg[10], cnt[10]
#define RPW    16     // rows per wave per iteration

// ---------------------------------------------------------------------------
// Register-lean streaming kernel. NO __launch_bounds__ min-waves arg: rounds
// 1/2/4 showed hipcc caps VGPRs at ~half the 512/min_waves formula
// (reported 128/64/32 for args 2/4/8), forcing scratch spill (GB-scale
// WRITE_SIZE). Let the allocator size itself (~45-60 VGPRs live set).
//
// Lane role: g = lane>>2 (row in 16-row tile), s4 = lane&3 (chunk slot).
// Lane loads chunks {s4, s4+4, s4+8, s4+12} of its row (4x float4 = 64B);
// 4-lane group covers the full row; 4 load insts cover the 4KB tile once.
//
// Per-k immediate pipeline (no sd[] array -> one dk live at a time):
//   dk = partial dot; 4-lane allreduce (xor 1,2); clip; exp;
//   owner lane (s4 == k&3) accumulates into static slot k>>2.
// Each (row,k) is accumulated by exactly one lane -> sums are exact 1x.
// Deterministic: fixed butterfly orders, per-wave partials, tree finalize.
// ---------------------------------------------------------------------------
__global__ __launch_bounds__(BLOCK) void cl_main(
    const float* __restrict__ feat, const int* __restrict__ pred,
    const float* __restrict__ centers, float* __restrict__ ws,
    int N, int nPart)
{
    __shared__ float4 c_lds[KC * D4];   // 2.5 KB
    const int tid = threadIdx.x;
    if (tid < KC * D4)
        c_lds[tid] = ((const float4*)centers)[tid];
    __syncthreads();

    const int lane = tid & 63;
    const int wave = tid >> 6;
    const int wgid = blockIdx.x * WPB + wave;   // 0..nPart-1
    const int s4   = lane & 3;
    const int g    = lane >> 2;

    // lane's clusters: k = s4, s4+4, s4+8 (slot2 real only for s4<2)
    float pos0=0.f,pos1=0.f,pos2=0.f, neg0=0.f,neg1=0.f,neg2=0.f,
          cnt0=0.f,cnt1=0.f,cnt2=0.f;

    const int nTiles = (N + RPW - 1) / RPW;
    for (int t = wgid; t < nTiles; t += nPart) {
        const int row  = t * RPW + g;
        const int rc   = row < N ? row : N - 1;
        const float4* rp = (const float4*)feat + (size_t)rc * D4 + s4;
        const float4 f0 = rp[0], f1 = rp[4], f2 = rp[8], f3 = rp[12];
        const int   pcur = pred[rc];
        const float actf = (row < N) ? 1.f : 0.f;

#pragma unroll
        for (int k = 0; k < KC; ++k) {
            const float4 c0 = c_lds[k * D4 + 0  + s4];
            const float4 c1 = c_lds[k * D4 + 4  + s4];
            const float4 c2 = c_lds[k * D4 + 8  + s4];
            const float4 c3 = c_lds[k * D4 + 12 + s4];
            float dk = f0.x*c0.x + f0.y*c0.y + f0.z*c0.z + f0.w*c0.w
                     + f1.x*c1.x + f1.y*c1.y + f1.z*c1.z + f1.w*c1.w
                     + f2.x*c2.x + f2.y*c2.y + f2.z*c2.z + f2.w*c2.w
                     + f3.x*c3.x + f3.y*c3.y + f3.z*c3.z + f3.w*c3.w;
            dk += __shfl_xor(dk, 1, 64);
            dk += __shfl_xor(dk, 2, 64);          // 4-lane allreduce: full dot

            const float sc = fminf(fmaxf(dk * 0.5f, -10.f), 10.f);
            const float e  = __expf(sc) * actf;
            const bool own = (s4 == (k & 3));     // unique owner per 4-lane group
            const bool hit = own && (pcur == k);
            const float eo = own ? e : 0.f;
            const float ep = hit ? e : 0.f;
            const float cp = hit ? actf : 0.f;
            // static accumulator slot k>>2 (loop fully unrolled)
            if ((k >> 2) == 0)      { neg0 += eo; pos0 += ep; cnt0 += cp; }
            else if ((k >> 2) == 1) { neg1 += eo; pos1 += ep; cnt1 += cp; }
            else                    { neg2 += eo; pos2 += ep; cnt2 += cp; }
        }
    }

    // ---- reduce across the 16 lanes sharing this s4 (offsets 4..32) ----
#pragma unroll
    for (int off = 4; off <= 32; off <<= 1) {
        pos0 += __shfl_xor(pos0, off, 64); neg0 += __shfl_xor(neg0, off, 64); cnt0 += __shfl_xor(cnt0, off, 64);
        pos1 += __shfl_xor(pos1, off, 64); neg1 += __shfl_xor(neg1, off, 64); cnt1 += __shfl_xor(cnt1, off, 64);
        pos2 += __shfl_xor(pos2, off, 64); neg2 += __shfl_xor(neg2, off, 64); cnt2 += __shfl_xor(cnt2, off, 64);
    }

    if (lane < 4) {           // lane == s4; write partials [q][nPart]
        const int k0 = lane, k1 = lane + 4, k2 = lane + 8;
        ws[(k0)          * nPart + wgid] = pos0;
        ws[(KC + k0)     * nPart + wgid] = neg0;
        ws[(2 * KC + k0) * nPart + wgid] = cnt0;
        ws[(k1)          * nPart + wgid] = pos1;
        ws[(KC + k1)     * nPart + wgid] = neg1;
        ws[(2 * KC + k1) * nPart + wgid] = cnt1;
        if (k2 < KC) {
            ws[(k2)          * nPart + wgid] = pos2;
            ws[(KC + k2)     * nPart + wgid] = neg2;
            ws[(2 * KC + k2) * nPart + wgid] = cnt2;
        }
    }
}

// ---------------------------------------------------------------------------
// Finalize: one block; float4 coalesced reads, static accumulator indexing,
// deterministic tree combine, thread 0 computes the scalar loss.
// ---------------------------------------------------------------------------
__global__ __launch_bounds__(BLOCK) void cl_final(
    const float* __restrict__ ws, float* __restrict__ out, int N, int nPart)
{
    const int tid = threadIdx.x;
    const int np4 = nPart >> 2;                 // nPart multiple of 4 (WPB)
    const float4* w4 = (const float4*)ws;

    float acc[NQ];
#pragma unroll
    for (int q = 0; q < NQ; ++q) acc[q] = 0.f;

    for (int i = tid; i < np4; i += BLOCK) {
#pragma unroll
        for (int q = 0; q < NQ; ++q) {          // q static -> registers
            const float4 v = w4[q * np4 + i];   // coalesced
            acc[q] += (v.x + v.y) + (v.z + v.w);
        }
    }

    const int wave = tid >> 6;
    const int lane = tid & 63;
    __shared__ float sred[WPB][NQ];
#pragma unroll
    for (int q = 0; q < NQ; ++q) {
        float v = acc[q];
#pragma unroll
        for (int off = 32; off; off >>= 1) v += __shfl_xor(v, off, 64);
        if (lane == 0) sred[wave][q] = v;
    }
    __syncthreads();

    if (tid == 0) {
        float tot = 0.f;
        int nv = 0;
#pragma unroll
        for (int k = 0; k < KC; ++k) {
            const float pos_s = sred[0][k]      + sred[1][k]      + sred[2][k]      + sred[3][k];
            const float neg_s = sred[0][KC+k]   + sred[1][KC+k]   + sred[2][KC+k]   + sred[3][KC+k];
            const float cnt   = sred[0][2*KC+k] + sred[1][2*KC+k] + sred[2][2*KC+k] + sred[3][2*KC+k];
            const float neg = neg_s / (float)N;                 // e.mean(axis=0)
            const float pos = pos_s / fmaxf(cnt, 1.f);          // sum / max(count,1)
            const float lt  = -logf(pos / (neg + 1e-8f));
            const bool valid = (cnt > 0.f) && (cnt < (float)N) &&
                               (pos > 1e-8f) && (neg > 1e-8f) && isfinite(lt);
            if (valid) { tot += lt; ++nv; }
        }
        out[0] = (nv > 0 ? tot / (float)nv : 0.f) * 5.0f;   // * weight
    }
}

extern "C" void kernel_launch(void* const* d_in, const int* in_sizes, int n_in,
                              void* d_out, int out_size, void* d_ws, size_t ws_size,
                              hipStream_t stream) {
    const float* feat    = (const float*)d_in[0];
    const int*   pred    = (const int*)d_in[1];
    const float* centers = (const float*)d_in[2];
    float*       out     = (float*)d_out;
    const int N = in_sizes[1];          // 500000

    int nPart = 4096;                               // 1024 blocks * 4 waves
    const int maxPart = (int)(ws_size / (NQ * sizeof(float)));
    if (nPart > maxPart) nPart = maxPart & ~(WPB - 1);
    if (nPart < WPB) nPart = WPB;
    const int nBlocks = nPart / WPB;

    hipLaunchKernelGGL(cl_main, dim3(nBlocks), dim3(BLOCK), 0, stream,
                       feat, pred, centers, (float*)d_ws, N, nPart);
    hipLaunchKernelGGL(cl_final, dim3(1), dim3(BLOCK), 0, stream,
                       (const float*)d_ws, out, N, nPart);
}

// Round 6
// 35.657 us; speedup vs baseline: 22.1168x; 1.5998x over previous
//
#include <hip/hip_runtime.h>
#include <math.h>

#define KC     10      // clusters
#define BLOCK  256
#define WPB    4       // waves per block
#define NQ     (3*KC)  // pos[10], neg[10], cnt[10]
#define NBLK   2048    // main-kernel blocks; ws partials = one per block
#define BLOCKF 1024    // finalize threads

typedef float v2f __attribute__((ext_vector_type(2)));
union F4 { float4 f; v2f h[2]; };

// 4-lane (quad) allreduce-add via DPP quad_perm — VALU, not DS pipe.
// 0xB1 = quad_perm[1,0,3,2] (xor 1), 0x4E = quad_perm[2,3,0,1] (xor 2).
__device__ __forceinline__ float quad_allreduce_add(float x) {
    int y = __builtin_amdgcn_update_dpp(0, __float_as_int(x), 0xB1, 0xF, 0xF, true);
    x += __int_as_float(y);
    y = __builtin_amdgcn_update_dpp(0, __float_as_int(x), 0x4E, 0xF, 0xF, true);
    return x + __int_as_float(y);
}

// ---------------------------------------------------------------------------
// Main kernel. Lane role: g = lane>>2 (row pair g, g+16 of a 32-row tile),
// s4 = lane&3 (16-float chunk slot). Lane loads its quarter of TWO rows
// (2 x 64B) -> center ds_reads amortize over 2 rows. Dots via packed-fp32
// (v_pk_fma_f32) v2f ops; quad allreduce via DPP. Lane s4 owns clusters
// {s4, s4+4, s4+8}: owned dots collected via static cndmask in the k-loop,
// exp/clip done once per owned slot per row (6 exps/lane/iter, not 20).
// Partials block-reduced via LDS -> ws[q][nBlocks]. Deterministic throughout.
// NO __launch_bounds__ min-waves arg (rounds 1/2/4: it forces spill).
// ---------------------------------------------------------------------------
__global__ __launch_bounds__(BLOCK) void cl_main(
    const float* __restrict__ feat, const int* __restrict__ pred,
    const float* __restrict__ centers, float* __restrict__ ws,
    int N, int nWaves, int nBlocks)
{
    __shared__ float4 c_lds[KC * 16];   // 2.5 KB
    __shared__ float  blk[WPB][NQ];
    const int tid = threadIdx.x;
    if (tid < KC * 16)
        c_lds[tid] = ((const float4*)centers)[tid];
    __syncthreads();

    const int lane = tid & 63;
    const int wave = tid >> 6;
    const int wgid = blockIdx.x * WPB + wave;
    const int s4   = lane & 3;
    const int g    = lane >> 2;

    float pos0=0.f,pos1=0.f,pos2=0.f, neg0=0.f,neg1=0.f,neg2=0.f,
          cnt0=0.f,cnt1=0.f,cnt2=0.f;

    const int nTiles = (N + 31) >> 5;           // 32 rows per tile
    for (int t = wgid; t < nTiles; t += nWaves) {
        const int rowA = (t << 5) + g;
        const int rowB = rowA + 16;
        const int rcA  = rowA < N ? rowA : N - 1;
        const int rcB  = rowB < N ? rowB : N - 1;
        const float4* rpA = (const float4*)feat + (size_t)rcA * 16 + s4;
        const float4* rpB = (const float4*)feat + (size_t)rcB * 16 + s4;
        F4 a0,a1,a2,a3, b0,b1,b2,b3;
        a0.f = rpA[0]; a1.f = rpA[4]; a2.f = rpA[8]; a3.f = rpA[12];
        b0.f = rpB[0]; b1.f = rpB[4]; b2.f = rpB[8]; b3.f = rpB[12];
        const int   pA = pred[rcA], pB = pred[rcB];
        const float actA = rowA < N ? 1.f : 0.f;
        const float actB = rowB < N ? 1.f : 0.f;

        float dA0=0.f,dA1=0.f,dA2=0.f, dB0=0.f,dB1=0.f,dB2=0.f;
#pragma unroll
        for (int k = 0; k < KC; ++k) {
            F4 c0,c1,c2,c3;
            c0.f = c_lds[k*16 + 0  + s4];
            c1.f = c_lds[k*16 + 4  + s4];
            c2.f = c_lds[k*16 + 8  + s4];
            c3.f = c_lds[k*16 + 12 + s4];
            v2f sA = a0.h[0]*c0.h[0]; sA += a0.h[1]*c0.h[1];
            sA += a1.h[0]*c1.h[0];    sA += a1.h[1]*c1.h[1];
            sA += a2.h[0]*c2.h[0];    sA += a2.h[1]*c2.h[1];
            sA += a3.h[0]*c3.h[0];    sA += a3.h[1]*c3.h[1];
            v2f sB = b0.h[0]*c0.h[0]; sB += b0.h[1]*c0.h[1];
            sB += b1.h[0]*c1.h[0];    sB += b1.h[1]*c1.h[1];
            sB += b2.h[0]*c2.h[0];    sB += b2.h[1]*c2.h[1];
            sB += b3.h[0]*c3.h[0];    sB += b3.h[1]*c3.h[1];
            const float dkA = quad_allreduce_add(sA.x + sA.y);
            const float dkB = quad_allreduce_add(sB.x + sB.y);
            const bool own = (s4 == (k & 3));   // unique owner per quad
            if ((k >> 2) == 0)      { dA0 = own ? dkA : dA0; dB0 = own ? dkB : dB0; }
            else if ((k >> 2) == 1) { dA1 = own ? dkA : dA1; dB1 = own ? dkB : dB1; }
            else                    { dA2 = own ? dkA : dA2; dB2 = own ? dkB : dB2; }
        }
        const float m2A = (s4 < 2) ? actA : 0.f;    // slot2 real only for s4<2
        const float m2B = (s4 < 2) ? actB : 0.f;
        {   // row A epilogue: owned clusters k = s4, s4+4, s4+8
            float e = __expf(fminf(fmaxf(dA0*0.5f,-10.f),10.f)) * actA;
            bool h = (pA == s4);      neg0 += e; pos0 += h?e:0.f; cnt0 += h?actA:0.f;
            e = __expf(fminf(fmaxf(dA1*0.5f,-10.f),10.f)) * actA;
            h = (pA == s4+4);         neg1 += e; pos1 += h?e:0.f; cnt1 += h?actA:0.f;
            e = __expf(fminf(fmaxf(dA2*0.5f,-10.f),10.f)) * m2A;
            h = (pA == s4+8);         neg2 += e; pos2 += h?e:0.f; cnt2 += h?m2A:0.f;
        }
        {   // row B epilogue
            float e = __expf(fminf(fmaxf(dB0*0.5f,-10.f),10.f)) * actB;
            bool h = (pB == s4);      neg0 += e; pos0 += h?e:0.f; cnt0 += h?actB:0.f;
            e = __expf(fminf(fmaxf(dB1*0.5f,-10.f),10.f)) * actB;
            h = (pB == s4+4);         neg1 += e; pos1 += h?e:0.f; cnt1 += h?actB:0.f;
            e = __expf(fminf(fmaxf(dB2*0.5f,-10.f),10.f)) * m2B;
            h = (pB == s4+8);         neg2 += e; pos2 += h?e:0.f; cnt2 += h?m2B:0.f;
        }
    }

    // reduce across the 16 lanes sharing this s4 (one-time; shfl fine here)
#pragma unroll
    for (int off = 4; off <= 32; off <<= 1) {
        pos0 += __shfl_xor(pos0, off, 64); neg0 += __shfl_xor(neg0, off, 64); cnt0 += __shfl_xor(cnt0, off, 64);
        pos1 += __shfl_xor(pos1, off, 64); neg1 += __shfl_xor(neg1, off, 64); cnt1 += __shfl_xor(cnt1, off, 64);
        pos2 += __shfl_xor(pos2, off, 64); neg2 += __shfl_xor(neg2, off, 64); cnt2 += __shfl_xor(cnt2, off, 64);
    }

    if (lane < 4) {             // lane == s4
        const int k0 = lane, k1 = lane + 4, k2 = lane + 8;
        blk[wave][k0] = pos0; blk[wave][KC + k0] = neg0; blk[wave][2*KC + k0] = cnt0;
        blk[wave][k1] = pos1; blk[wave][KC + k1] = neg1; blk[wave][2*KC + k1] = cnt1;
        if (k2 < KC) {
            blk[wave][k2] = pos2; blk[wave][KC + k2] = neg2; blk[wave][2*KC + k2] = cnt2;
        }
    }
    __syncthreads();
    if (tid < NQ) {             // block partial, layout [q][nBlocks]
        const float s = blk[0][tid] + blk[1][tid] + blk[2][tid] + blk[3][tid];
        ws[(size_t)tid * nBlocks + blockIdx.x] = s;
    }
}

// ---------------------------------------------------------------------------
// Finalize: 1024 threads; 32-thread group per quantity q (30 active groups),
// float4 coalesced reads, fixed-order butterfly, thread 0 computes the loss.
// ---------------------------------------------------------------------------
__global__ __launch_bounds__(BLOCKF) void cl_final(
    const float* __restrict__ ws, float* __restrict__ out, int N, int nBlocks)
{
    const int tid = threadIdx.x;
    const int grp = tid >> 5, sub = tid & 31;
    __shared__ float sq[NQ];

    float acc = 0.f;
    if (grp < NQ) {
        const float4* w4 = (const float4*)(ws + (size_t)grp * nBlocks);
        const int n4 = nBlocks >> 2;
        for (int i = sub; i < n4; i += 32) {
            const float4 v = w4[i];
            acc += (v.x + v.y) + (v.z + v.w);
        }
    }
#pragma unroll
    for (int off = 1; off <= 16; off <<= 1) acc += __shfl_xor(acc, off, 64);
    if (grp < NQ && sub == 0) sq[grp] = acc;
    __syncthreads();

    if (tid == 0) {
        float tot = 0.f;
        int nv = 0;
#pragma unroll
        for (int k = 0; k < KC; ++k) {
            const float pos_s = sq[k];
            const float neg_s = sq[KC + k];
            const float cnt   = sq[2*KC + k];
            const float neg = neg_s / (float)N;             // e.mean(axis=0)
            const float pos = pos_s / fmaxf(cnt, 1.f);      // sum / max(count,1)
            const float lt  = -logf(pos / (neg + 1e-8f));
            const bool valid = (cnt > 0.f) && (cnt < (float)N) &&
                               (pos > 1e-8f) && (neg > 1e-8f) && isfinite(lt);
            if (valid) { tot += lt; ++nv; }
        }
        out[0] = (nv > 0 ? tot / (float)nv : 0.f) * 5.0f;   // * weight
    }
}

extern "C" void kernel_launch(void* const* d_in, const int* in_sizes, int n_in,
                              void* d_out, int out_size, void* d_ws, size_t ws_size,
                              hipStream_t stream) {
    const float* feat    = (const float*)d_in[0];
    const int*   pred    = (const int*)d_in[1];
    const float* centers = (const float*)d_in[2];
    float*       out     = (float*)d_out;
    const int N = in_sizes[1];          // 500000

    int nBlocks = NBLK;
    const int maxB = (int)(ws_size / (NQ * sizeof(float)));
    if (nBlocks > maxB) nBlocks = maxB & ~3;
    if (nBlocks < 4) nBlocks = 4;
    const int nWaves = nBlocks * WPB;

    hipLaunchKernelGGL(cl_main, dim3(nBlocks), dim3(BLOCK), 0, stream,
                       feat, pred, centers, (float*)d_ws, N, nWaves, nBlocks);
    hipLaunchKernelGGL(cl_final, dim3(1), dim3(BLOCKF), 0, stream,
                       (const float*)d_ws, out, N, nBlocks);
}